// Round 8
// baseline (534.152 us; speedup 1.0000x reference)
//
#include <hip/hip_runtime.h>
#include <hip/hip_bf16.h>
#include <cstdint>

#define B_   2
#define T_   4096
#define D_   1024
#define H_   16
#define DH_  64
#define M_   (B_*T_)     // 8192 rows
#define K3_  (3*D_)      // 3072
#define TC_  128         // cumsum chunk
#define NCH_ (T_/TC_)    // 32 chunks

typedef __attribute__((ext_vector_type(4))) float  f32x4;
typedef __attribute__((ext_vector_type(8))) short  short8;

__device__ __forceinline__ float bf2f(ushort u) {
    union { uint32_t i; float f; } v; v.i = ((uint32_t)u) << 16; return v.f;
}
__device__ __forceinline__ ushort f2bf(float f) {
    union { float f; uint32_t i; } v; v.f = f;
    uint32_t r = v.i + 0x7FFF + ((v.i >> 16) & 1);
    return (ushort)(r >> 16);
}

template<bool F32>
__device__ __forceinline__ float ld_in(const void* p, size_t i) {
    if (F32) return ((const float*)p)[i];
    return bf2f(((const ushort*)p)[i]);
}

// store helpers: bf16 internal buffers vs f32 final output
__device__ __forceinline__ void st_c(ushort* p, float v) { *p = f2bf(v); }
__device__ __forceinline__ void st_c(float*  p, float v) { *p = v; }

#define GLOAD_LDS16(g, l) \
    __builtin_amdgcn_global_load_lds((const __attribute__((address_space(1))) void*)(g), \
                                     (__attribute__((address_space(3))) void*)(l), 16, 0, 0)

// ---------------- P0: dtype detector ----------------
__global__ void detect_kernel(const ushort* __restrict__ xu, int* __restrict__ flag) {
    __shared__ int cnt;
    if (threadIdx.x == 0) cnt = 0;
    __syncthreads();
    int c = 0;
    for (int i = threadIdx.x; i < 16384; i += 256) {
        ushort u = xu[i];
        if ((u & 0x7F80) == 0x7F80) c++;
    }
    if (c) atomicAdd(&cnt, c);
    __syncthreads();
    if (threadIdx.x == 0) flag[0] = (cnt > 0) ? 1 : 0;
}

// ---------------- P1: gates -> telescoping chain ratios ----------------
// g9[row][p*3+s] stores: s=0: g0/g1', s=1: g1'/g2', s=2: g2'  (g'=max(g,1e-30))
template<bool F32>
__device__ __forceinline__ void gates_body(const void* x,
                                           const void* Wg_q, const void* bg_q,
                                           const void* Wg_k, const void* bg_k,
                                           const void* Wg_v, const void* bg_v,
                                           float* __restrict__ g9) {
    const int wave = threadIdx.x >> 6, lane = threadIdx.x & 63;
    const int row  = blockIdx.x * 4 + wave;
    const size_t xoff = (size_t)row * D_;
    float acc[9] = {0,0,0,0,0,0,0,0,0};
    for (int d = lane; d < D_; d += 64) {
        float xv = ld_in<F32>(x, xoff + d);
        #pragma unroll
        for (int c = 0; c < 3; c++) {
            acc[0+c] += xv * ld_in<F32>(Wg_q, d*3+c);
            acc[3+c] += xv * ld_in<F32>(Wg_k, d*3+c);
            acc[6+c] += xv * ld_in<F32>(Wg_v, d*3+c);
        }
    }
    #pragma unroll
    for (int i = 0; i < 9; i++) {
        #pragma unroll
        for (int o = 32; o >= 1; o >>= 1) acc[i] += __shfl_xor(acc[i], o, 64);
    }
    const void* bgs[3] = {bg_q, bg_k, bg_v};
    float g[9];
    #pragma unroll
    for (int p = 0; p < 3; p++) {
        float l0 = acc[p*3+0] + ld_in<F32>(bgs[p], 0);
        float l1 = acc[p*3+1] + ld_in<F32>(bgs[p], 1);
        float l2 = acc[p*3+2] + ld_in<F32>(bgs[p], 2);
        float mx = fmaxf(l0, fmaxf(l1, l2));
        float e0 = expf(l0-mx), e1 = expf(l1-mx), e2 = expf(l2-mx);
        float s  = e0+e1+e2;
        float g0 = fminf(e0/s, 0.6f), g1 = fminf(e1/s, 0.6f), g2 = fminf(e2/s, 0.6f);
        float s2 = g0+g1+g2;
        g0 /= s2; g1 /= s2; g2 /= s2;
        float g1c = fmaxf(g1, 1e-30f), g2c = fmaxf(g2, 1e-30f);
        g[p*3+0] = g0 / g1c;
        g[p*3+1] = g1c / g2c;
        g[p*3+2] = g2c;
    }
    if (lane == 0) {
        #pragma unroll
        for (int i = 0; i < 9; i++) g9[(size_t)row*9 + i] = g[i];
    }
}
__global__ void gates_kernel(const void* x,
                             const void* Wg_q, const void* bg_q,
                             const void* Wg_k, const void* bg_k,
                             const void* Wg_v, const void* bg_v,
                             const int* __restrict__ flag, float* __restrict__ g9) {
    if (flag[0]) gates_body<true >(x, Wg_q, bg_q, Wg_k, bg_k, Wg_v, bg_v, g9);
    else         gates_body<false>(x, Wg_q, bg_q, Wg_k, bg_k, Wg_v, bg_v, g9);
}

// ---------------- P2: per-chunk sums ----------------
template<bool F32>
__device__ __forceinline__ void chunk_sum_body(const void* x, float* __restrict__ part) {
    const int d = blockIdx.x * 256 + threadIdx.x;
    const int tc = blockIdx.y, b = blockIdx.z;
    const size_t base = ((size_t)b*T_ + (size_t)tc*TC_) * D_ + d;
    float s = 0.f;
    for (int i = 0; i < TC_; i++) s += ld_in<F32>(x, base + (size_t)i * D_);
    part[((size_t)b*NCH_ + tc) * D_ + d] = s;
}
__global__ void chunk_sum_kernel(const void* x, const int* __restrict__ flag,
                                 float* __restrict__ part) {
    if (flag[0]) chunk_sum_body<true >(x, part);
    else         chunk_sum_body<false>(x, part);
}

// ---------------- P3: exclusive scan of chunk sums ----------------
__global__ void scan_part_kernel(float* __restrict__ part) {
    const int idx = blockIdx.x * 256 + threadIdx.x;   // 0..2047
    const int b = idx >> 10, d = idx & (D_-1);
    float run = 0.f;
    for (int tc = 0; tc < NCH_; tc++) {
        size_t o = ((size_t)b*NCH_ + tc) * D_ + d;
        float v = part[o]; part[o] = run; run += v;
    }
}

// ---------------- P4: build UNSCALED concat input Xc[row] = [x | integ | deriv] ----------------
template<bool F32>
__device__ __forceinline__ void build_xs_body(const void* x, const float* __restrict__ part,
                                              ushort* __restrict__ Xc) {
    const int d0 = (blockIdx.x * 256 + threadIdx.x) * 2;
    const int tc = blockIdx.y, b = blockIdx.z;
    const int t0 = tc * TC_;
    float carry0 = part[((size_t)b*NCH_ + tc) * D_ + d0];
    float carry1 = part[((size_t)b*NCH_ + tc) * D_ + d0 + 1];
    const size_t xbase = ((size_t)b*T_ + t0) * D_ + d0;
    float prev0 = (t0 > 0) ? ld_in<F32>(x, xbase - D_)     : 0.0f;
    float prev1 = (t0 > 0) ? ld_in<F32>(x, xbase - D_ + 1) : 0.0f;
    for (int i = 0; i < TC_; i++) {
        const int t = t0 + i;
        float xv0 = ld_in<F32>(x, xbase + (size_t)i * D_);
        float xv1 = ld_in<F32>(x, xbase + (size_t)i * D_ + 1);
        carry0 += xv0; carry1 += xv1;
        const float rinv = 1.0f / (float)(t + 1);
        float in0 = carry0 * rinv, in1 = carry1 * rinv;
        float de0 = (t == 0) ? 0.0f : (xv0 - prev0);
        float de1 = (t == 0) ? 0.0f : (xv1 - prev1);
        prev0 = xv0; prev1 = xv1;
        const size_t base = ((size_t)b*T_ + t) * K3_ + d0;
        *(ushort2*)(Xc + base       ) = make_ushort2(f2bf(xv0), f2bf(xv1));
        *(ushort2*)(Xc + base +   D_) = make_ushort2(f2bf(in0), f2bf(in1));
        *(ushort2*)(Xc + base + 2*D_) = make_ushort2(f2bf(de0), f2bf(de1));
    }
}
__global__ void build_xs_kernel(const void* x, const float* __restrict__ part,
                                const int* __restrict__ flag, ushort* __restrict__ Xc) {
    if (flag[0]) build_xs_body<true >(x, part, Xc);
    else         build_xs_body<false>(x, part, Xc);
}

// ---------------- P5: weight transpose -> (N,K) bf16 ----------------
struct WPtrs { const void* w[10]; };
template<bool F32>
__device__ __forceinline__ void transpose_w_body(WPtrs ptrs, ushort* __restrict__ Wt,
                                                 ushort* __restrict__ WoT) {
    const int z = blockIdx.z;                 // 0..8: W{p,j}; 9: Wo
    const void* src = ptrs.w[z];
    __shared__ float tile[32][33];
    const int tx = threadIdx.x & 31, ty = threadIdx.x >> 5;
    const int d0 = blockIdx.x * 32, c0 = blockIdx.y * 32;
    #pragma unroll
    for (int i = 0; i < 4; i++) {
        int r = ty + i*8;
        tile[r][tx] = ld_in<F32>(src, (size_t)(d0 + r) * D_ + c0 + tx);
    }
    __syncthreads();
    if (z < 9) {
        const int p = z / 3, j = z % 3;
        #pragma unroll
        for (int i = 0; i < 4; i++) {
            int r = ty + i*8;
            Wt[(size_t)(p*D_ + c0 + r) * K3_ + j*D_ + d0 + tx] = f2bf(tile[tx][r]);
        }
    } else {
        #pragma unroll
        for (int i = 0; i < 4; i++) {
            int r = ty + i*8;
            WoT[(size_t)(c0 + r) * D_ + d0 + tx] = f2bf(tile[tx][r]);
        }
    }
}
__global__ void transpose_w_kernel(WPtrs ptrs, const int* __restrict__ flag,
                                   ushort* __restrict__ Wt, ushort* __restrict__ WoT) {
    if (flag[0]) transpose_w_body<true >(ptrs, Wt, WoT);
    else         transpose_w_body<false>(ptrs, Wt, WoT);
}

// ---------------- QKV GEMM v8: 256x256, BK=64, dbuf, SELF-CONTAINED phases --
// C(8192x3072) = Xc * Wt^T, bf16 in/out, f32 acc, gated.
// 8 waves 2Mx4N -> per-wave 128x64, acc[8][4] = 128 AGPR.
// Unified-regfile budget: 512-thr block => 2 waves/SIMD => 256 regs/wave cap.
// 128 AGPR (acc) leaves 128 arch VGPRs. r7 spilled because bfr was held
// across 3 barrier boundaries + lgkm0/sched_barrier pins froze live ranges.
// v8: each phase re-reads its own af[4]+bfr[4] (nothing lives across a
// barrier but acc + loop invariants ~90 regs), and drops ALL manual lgkmcnt/
// sched_barrier: the ds_reads are plain loads, so the compiler emits its own
// counted lgkmcnt(N) per dependent MFMA (m97-verified; rule 18 applies only
// to asm reads). Raw s_barrier before the MFMA block stays: waves converge
// while reads are in flight; counted vmcnt ledger (r6/r7-proven) unchanged.
// LDS traffic 16 reads/tile/wave = 128 KB/CU/tile ~1500cyc < 2060cyc MFMA.
//
// Swizzle (r4/r7 HW-verified, 0 conflicts): ds_read_b128 is serviced in
// 8-lane runs; read octet = quad ^ ((l16>>1)&3) makes each run cover all 8
// bank-quads. Storage: source octet (tid&3)^((tid>>3)&3), linear LDS dest.
//
// vmcnt ledger (2 gloads per phase, slab order A0,B0,A1,B1 of t+1):
//   end-P2(t): outstanding = A1,B1(t)[4] + A0,B0(t+1)[4] -> vmcnt(4) proves
//   A1,B1(t) for P3/P4. end-P4(t): outstanding = A0,B0(t+1) + A1,B1(t+1)
//   -> vmcnt(4) proves A0,B0(t+1) for next P1. Drain 0 only at t==NT-1.
__global__ __launch_bounds__(512, 2) void gemm_qkv_kernel(
        const ushort* __restrict__ Abase,
        const ushort* __restrict__ Bt,
        ushort* __restrict__ C,
        const float* __restrict__ g9) {
    constexpr int NT   = K3_ / 64;       // 48 K-tiles
    constexpr int RSTR = 128 * K3_;      // +128 rows, ushorts
    __shared__ __align__(16) ushort LDS[2 * 32768];   // 131072 B
    const int tid  = threadIdx.x;
    const int lane = tid & 63;
    const int wave = tid >> 6;
    const int wm   = wave >> 2;          // 0..1
    const int wn   = wave & 3;           // 0..3
    const int quad = lane >> 4, l16 = lane & 15;
    const int apos = (quad ^ ((l16 >> 1) & 3)) * 8;  // HW-verified swizzle

    // XCD-chunked bijective: 384 blocks, cpx=48; per-XCD 4mt x 12nt chunk
    const int wg  = ((int)blockIdx.x % 8) * 48 + (int)blockIdx.x / 8;
    const int rem = wg % 48;
    const int mt  = (wg / 48) * 4 + (rem & 3);
    const int nt  = rem >> 2;            // 0..11
    const int m0  = mt * 256;
    const int n0  = nt * 256;
    const int p   = n0 >> 10;            // projection, uniform per block

    // staging: thread covers rows {tid>>2, +128} of A and B; source logical
    // octet = (tid&3) ^ ((tid>>3)&3) (inverse of storage swizzle).
    const int j8 = ((tid & 3) ^ ((tid >> 3) & 3)) * 8;
    const ushort* pA = Abase + (size_t)(m0 + (tid >> 2)) * K3_ + j8;
    const ushort* pB = Bt    + (size_t)(n0 + (tid >> 2)) * K3_ + j8;
    const int d0 = tid * 8;              // LDS dest granule (rows 0..127)
    const int d1 = (512 + tid) * 8;      // rows 128..255

    // scalar read bases (within buffer); af[i] at +i*512, bfr[j] at +j*512
    const int ab0 = (wm*128 + l16) * 32 + apos;
    const int bb0 = 16384 + (wn*64 + l16) * 32 + apos;

    f32x4 acc[8][4] = {};

    // ---- prologue: stage tile 0 -> buf0, order A_k0, B_k0, A_k1, B_k1 ----
    GLOAD_LDS16(pA,             &LDS[d0]);
    GLOAD_LDS16(pA + RSTR,      &LDS[d1]);
    GLOAD_LDS16(pB,             &LDS[16384 + d0]);
    GLOAD_LDS16(pB + RSTR,      &LDS[16384 + d1]);
    GLOAD_LDS16(pA + 32,        &LDS[8192 + d0]);
    GLOAD_LDS16(pA + RSTR + 32, &LDS[8192 + d1]);
    GLOAD_LDS16(pB + 32,        &LDS[24576 + d0]);
    GLOAD_LDS16(pB + RSTR + 32, &LDS[24576 + d1]);
    asm volatile("s_waitcnt vmcnt(4)" ::: "memory");   // A_k0,B_k0 landed
    __builtin_amdgcn_s_barrier();

    for (int t = 0; t < NT; ++t) {
        const int bb = (t & 1) << 15;    // compute buffer base (elems)
        const int sb = bb ^ 32768;       // staging buffer base
        const int sk = (t + 1) * 64;
        const bool stage = (t + 1 < NT);
        short8 af[4], bfr[4];

        // ---- phase 1: kk0, i0-3 | stage A_k0(t+1) ----
        #pragma unroll
        for (int i = 0; i < 4; i++) af[i]  = *(const short8*)&LDS[bb + ab0 + i*512];
        #pragma unroll
        for (int j = 0; j < 4; j++) bfr[j] = *(const short8*)&LDS[bb + bb0 + j*512];
        if (stage) {
            GLOAD_LDS16(pA + sk,        &LDS[sb + d0]);
            GLOAD_LDS16(pA + RSTR + sk, &LDS[sb + d1]);
        }
        __builtin_amdgcn_s_barrier();
        __builtin_amdgcn_s_setprio(1);
        #pragma unroll
        for (int i = 0; i < 4; i++)
            #pragma unroll
            for (int j = 0; j < 4; j++)
                acc[i][j] = __builtin_amdgcn_mfma_f32_16x16x32_bf16(af[i], bfr[j], acc[i][j], 0, 0, 0);
        __builtin_amdgcn_s_setprio(0);
        __builtin_amdgcn_s_barrier();

        // ---- phase 2: kk0, i4-7 (bfr re-read) | stage B_k0(t+1) ----
        #pragma unroll
        for (int i = 0; i < 4; i++) af[i]  = *(const short8*)&LDS[bb + ab0 + (4+i)*512];
        #pragma unroll
        for (int j = 0; j < 4; j++) bfr[j] = *(const short8*)&LDS[bb + bb0 + j*512];
        if (stage) {
            GLOAD_LDS16(pB + sk,        &LDS[sb + 16384 + d0]);
            GLOAD_LDS16(pB + RSTR + sk, &LDS[sb + 16384 + d1]);
        }
        __builtin_amdgcn_s_barrier();
        __builtin_amdgcn_s_setprio(1);
        #pragma unroll
        for (int i = 0; i < 4; i++)
            #pragma unroll
            for (int j = 0; j < 4; j++)
                acc[4+i][j] = __builtin_amdgcn_mfma_f32_16x16x32_bf16(af[i], bfr[j], acc[4+i][j], 0, 0, 0);
        __builtin_amdgcn_s_setprio(0);
        // ledger: prove A_k1,B_k1(t) landed before P3/P4 read them
        if (stage) asm volatile("s_waitcnt vmcnt(4)" ::: "memory");
        else       asm volatile("s_waitcnt vmcnt(0)" ::: "memory");
        __builtin_amdgcn_s_barrier();

        // ---- phase 3: kk1, i0-3 | stage A_k1(t+1) ----
        #pragma unroll
        for (int i = 0; i < 4; i++) af[i]  = *(const short8*)&LDS[bb + 8192 + ab0 + i*512];
        #pragma unroll
        for (int j = 0; j < 4; j++) bfr[j] = *(const short8*)&LDS[bb + 8192 + bb0 + j*512];
        if (stage) {
            GLOAD_LDS16(pA + sk + 32,        &LDS[sb + 8192 + d0]);
            GLOAD_LDS16(pA + RSTR + sk + 32, &LDS[sb + 8192 + d1]);
        }
        __builtin_amdgcn_s_barrier();
        __builtin_amdgcn_s_setprio(1);
        #pragma unroll
        for (int i = 0; i < 4; i++)
            #pragma unroll
            for (int j = 0; j < 4; j++)
                acc[i][j] = __builtin_amdgcn_mfma_f32_16x16x32_bf16(af[i], bfr[j], acc[i][j], 0, 0, 0);
        __builtin_amdgcn_s_setprio(0);
        __builtin_amdgcn_s_barrier();

        // ---- phase 4: kk1, i4-7 (bfr re-read) | stage B_k1(t+1) ----
        #pragma unroll
        for (int i = 0; i < 4; i++) af[i]  = *(const short8*)&LDS[bb + 8192 + ab0 + (4+i)*512];
        #pragma unroll
        for (int j = 0; j < 4; j++) bfr[j] = *(const short8*)&LDS[bb + 8192 + bb0 + j*512];
        if (stage) {
            GLOAD_LDS16(pB + sk + 32,        &LDS[sb + 24576 + d0]);
            GLOAD_LDS16(pB + RSTR + sk + 32, &LDS[sb + 24576 + d1]);
        }
        __builtin_amdgcn_s_barrier();
        __builtin_amdgcn_s_setprio(1);
        #pragma unroll
        for (int i = 0; i < 4; i++)
            #pragma unroll
            for (int j = 0; j < 4; j++)
                acc[4+i][j] = __builtin_amdgcn_mfma_f32_16x16x32_bf16(af[i], bfr[j], acc[4+i][j], 0, 0, 0);
        __builtin_amdgcn_s_setprio(0);
        // ledger: prove A_k0,B_k0(t+1) landed before next P1 reads them
        if (stage) asm volatile("s_waitcnt vmcnt(4)" ::: "memory");
        __builtin_amdgcn_s_barrier();

        if ((t & 15) == 15) {
            // telescoping gate fold: acc *= ratio[row, seg]; register-only
            const int seg = t >> 4;
            #pragma unroll
            for (int i = 0; i < 8; i++) {
                #pragma unroll
                for (int rg = 0; rg < 4; rg++) {
                    const int rrow = m0 + wm*128 + i*16 + quad*4 + rg;
                    const float gv = g9[(size_t)rrow * 9 + p*3 + seg];
                    #pragma unroll
                    for (int j = 0; j < 4; j++)
                        acc[i][j][rg] *= gv;
                }
            }
        }
    }

    // epilogue: C/D layout col=lane&15, row=quad*4+reg  [m89/m91 verified]
    #pragma unroll
    for (int i = 0; i < 8; i++) {
        #pragma unroll
        for (int j = 0; j < 4; j++) {
            const int rrow = m0 + wm*128 + i*16 + quad*4;
            const int col  = n0 + wn*64 + j*16 + l16;
            #pragma unroll
            for (int rg = 0; rg < 4; rg++)
                C[(size_t)(rrow + rg) * K3_ + col] = f2bf(acc[i][j][rg]);
        }
    }
}

// ---------------- out-proj GEMM (round-1 kernel, proven): 128x256 tile ------
template<typename CT, int NTILES, bool GATED>
__global__ __launch_bounds__(512, 2) void gemm_bt8_kernel(
        const ushort* __restrict__ Abase,
        const ushort* __restrict__ Bt,
        CT* __restrict__ C,
        const float* __restrict__ g9,
        int K, int lda, int ldc) {
    __shared__ __align__(16) ushort LDS[3 * 24576];
    const int tid  = threadIdx.x;
    const int lane = tid & 63;
    const int wave = tid >> 6;
    const int wm   = wave >> 2;
    const int wn   = wave & 3;
    const int quad = lane >> 4, l16 = lane & 15, sw = l16 & 7;

    const int MT     = M_ / 128;                 // 64
    const int cpx    = (MT * NTILES) / 8;
    const int wg     = (blockIdx.x % 8) * cpx + blockIdx.x / 8;
    const int mchunk = MT / 8;                   // 8
    const int rem    = wg % (mchunk * NTILES);
    const int mt     = (wg / (mchunk * NTILES)) * mchunk + (rem % mchunk);
    const int nt     = rem / mchunk;
    const int m0 = mt * 128;
    const int n0 = nt * 256;
    const int p  = n0 >> 10;

    const ushort* asrc[2]; int aoff[2];
    #pragma unroll
    for (int g = 0; g < 2; g++) {
        const int I = g*512 + tid;
        const int row = I >> 3, c8 = (I & 7) ^ (row & 7);
        asrc[g] = Abase + (size_t)(m0 + row) * lda + c8*8;
        aoff[g] = I * 8;
    }
    const ushort* bsrc[4]; int boff[4];
    #pragma unroll
    for (int g = 0; g < 4; g++) {
        const int I = g*512 + tid;
        const int row = I >> 3, c8 = (I & 7) ^ (row & 7);
        bsrc[g] = Bt + (size_t)(n0 + row) * K + c8*8;
        boff[g] = I * 8;
    }
    int ard[4], brd[4];
    #pragma unroll
    for (int i = 0; i < 4; i++) {
        ard[i] = (wm*64 + i*16 + l16) * 64;
        brd[i] = (wn*64 + i*16 + l16) * 64;
    }

    const int NKT = K >> 6;
    f32x4 acc[4][4] = {};

    #pragma unroll
    for (int g = 0; g < 2; g++) GLOAD_LDS16(asrc[g], &LDS[aoff[g]]);
    #pragma unroll
    for (int g = 0; g < 4; g++) GLOAD_LDS16(bsrc[g], &LDS[8192 + boff[g]]);
    #pragma unroll
    for (int g = 0; g < 2; g++) GLOAD_LDS16(asrc[g] + 64, &LDS[24576 + aoff[g]]);
    #pragma unroll
    for (int g = 0; g < 4; g++) GLOAD_LDS16(bsrc[g] + 64, &LDS[24576 + 8192 + boff[g]]);
    asm volatile("s_waitcnt vmcnt(6)" ::: "memory");
    __builtin_amdgcn_s_barrier();

    for (int t = 0; t < NKT; ++t) {
        const int cur = t % 3;
        const int ab  = cur * 24576;
        const int bb  = ab + 8192;
        const bool do_stage = (t + 2 < NKT);
        const int sb  = ((t + 2) % 3) * 24576;
        const int skt = (t + 2) << 6;

        short8 af[4], bfr[4];

        #pragma unroll
        for (int i = 0; i < 4; i++)
            af[i]  = *(const short8*)&LDS[ab + ard[i] + (quad ^ sw) * 8];
        #pragma unroll
        for (int j = 0; j < 4; j++)
            bfr[j] = *(const short8*)&LDS[bb + brd[j] + (quad ^ sw) * 8];
        if (do_stage) {
            GLOAD_LDS16(asrc[0] + skt, &LDS[sb + aoff[0]]);
            GLOAD_LDS16(asrc[1] + skt, &LDS[sb + aoff[1]]);
            GLOAD_LDS16(bsrc[0] + skt, &LDS[sb + 8192 + boff[0]]);
        }
        __builtin_amdgcn_s_barrier();
        asm volatile("s_waitcnt lgkmcnt(0)" ::: "memory");
        __builtin_amdgcn_sched_barrier(0);
        __builtin_amdgcn_s_setprio(1);
        #pragma unroll
        for (int i = 0; i < 4; i++)
            #pragma unroll
            for (int j = 0; j < 4; j++)
                acc[i][j] = __builtin_amdgcn_mfma_f32_16x16x32_bf16(af[i], bfr[j], acc[i][j], 0, 0, 0);
        __builtin_amdgcn_s_setprio(0);
        __builtin_amdgcn_s_barrier();

        #pragma unroll
        for (int i = 0; i < 4; i++)
            af[i]  = *(const short8*)&LDS[ab + ard[i] + ((quad + 4) ^ sw) * 8];
        #pragma unroll
        for (int j = 0; j < 4; j++)
            bfr[j] = *(const short8*)&LDS[bb + brd[j] + ((quad + 4) ^ sw) * 8];
        if (do_stage) {
            GLOAD_LDS16(bsrc[1] + skt, &LDS[sb + 8192 + boff[1]]);
            GLOAD_LDS16(bsrc[2] + skt, &LDS[sb + 8192 + boff[2]]);
            GLOAD_LDS16(bsrc[3] + skt, &LDS[sb + 8192 + boff[3]]);
        }
        __builtin_amdgcn_s_barrier();
        asm volatile("s_waitcnt lgkmcnt(0)" ::: "memory");
        __builtin_amdgcn_sched_barrier(0);
        __builtin_amdgcn_s_setprio(1);
        #pragma unroll
        for (int i = 0; i < 4; i++)
            #pragma unroll
            for (int j = 0; j < 4; j++)
                acc[i][j] = __builtin_amdgcn_mfma_f32_16x16x32_bf16(af[i], bfr[j], acc[i][j], 0, 0, 0);
        __builtin_amdgcn_s_setprio(0);
        if (do_stage)          asm volatile("s_waitcnt vmcnt(6)" ::: "memory");
        else if (t + 1 < NKT)  asm volatile("s_waitcnt vmcnt(0)" ::: "memory");
        __builtin_amdgcn_s_barrier();

        if (GATED && ((t & 15) == 15)) {
            const int seg = t >> 4;
            #pragma unroll
            for (int i = 0; i < 4; i++) {
                float gv[4];
                #pragma unroll
                for (int rg = 0; rg < 4; rg++) {
                    const int rrow = m0 + wm*64 + i*16 + quad*4 + rg;
                    gv[rg] = g9[(size_t)rrow * 9 + p*3 + seg];
                }
                #pragma unroll
                for (int j = 0; j < 4; j++)
                    #pragma unroll
                    for (int rg = 0; rg < 4; rg++)
                        acc[i][j][rg] *= gv[rg];
            }
        }
    }

    #pragma unroll
    for (int i = 0; i < 4; i++) {
        #pragma unroll
        for (int j = 0; j < 4; j++) {
            const int rrow = m0 + wm*64 + i*16 + quad*4;
            const int col  = n0 + wn*64 + j*16 + l16;
            #pragma unroll
            for (int rg = 0; rg < 4; rg++)
                st_c(&C[(size_t)(rrow + rg) * ldc + col], acc[i][j][rg]);
        }
    }
}

// ---------------- attention: one block per (b,t), all 16 heads ----------------
__global__ __launch_bounds__(256) void attn_kernel(const ushort* __restrict__ QKV,
                                                   ushort* __restrict__ AO) {
    const int tid = threadIdx.x;
    const int bt  = blockIdx.x;              // b*T_ + t
    const int t   = bt & (T_-1);
    const size_t qrow = (size_t)bt * K3_;
    const int e0 = tid * 4;

    const ushort4 q4 = *(const ushort4*)(QKV + qrow + e0);
    const float qf0 = bf2f(q4.x), qf1 = bf2f(q4.y), qf2 = bf2f(q4.z), qf3 = bf2f(q4.w);

    float sc[14];
    #pragma unroll
    for (int a = 0; a < 14; a++) {
        const int off = (a <= 3) ? a : (1 << (a - 2));
        float p = -1e30f;
        if (off <= t) {                      // block-uniform
            const ushort4 k4 = *(const ushort4*)(QKV + qrow - (size_t)off*K3_ + D_ + e0);
            float pp = qf0*bf2f(k4.x) + qf1*bf2f(k4.y) + qf2*bf2f(k4.z) + qf3*bf2f(k4.w);
            pp += __shfl_xor(pp, 1, 64);
            pp += __shfl_xor(pp, 2, 64);
            pp += __shfl_xor(pp, 4, 64);
            pp += __shfl_xor(pp, 8, 64);
            p = pp * 0.125f;                 // DH^-0.5
        }
        sc[a] = p;
    }
    float mx = -1e30f;
    #pragma unroll
    for (int a = 0; a < 14; a++) mx = fmaxf(mx, sc[a]);
    float ev[14], s = 0.0f;
    #pragma unroll
    for (int a = 0; a < 14; a++) { ev[a] = (sc[a] > -1e29f) ? expf(sc[a] - mx) : 0.0f; s += ev[a]; }
    const float rs = 1.0f / s;

    float a0 = 0.f, a1 = 0.f, a2 = 0.f, a3 = 0.f;
    #pragma unroll
    for (int a = 0; a < 14; a++) {
        const int off = (a <= 3) ? a : (1 << (a - 2));
        if (off <= t) {
            const ushort4 v4 = *(const ushort4*)(QKV + qrow - (size_t)off*K3_ + 2*D_ + e0);
            const float w = ev[a] * rs;
            a0 += w * bf2f(v4.x); a1 += w * bf2f(v4.y);
            a2 += w * bf2f(v4.z); a3 += w * bf2f(v4.w);
        }
    }
    ushort* dst = AO + (size_t)bt * D_ + e0;
    dst[0] = f2bf(a0); dst[1] = f2bf(a1); dst[2] = f2bf(a2); dst[3] = f2bf(a3);
}

extern "C" void kernel_launch(void* const* d_in, const int* in_sizes, int n_in,
                              void* d_out, int out_size, void* d_ws, size_t ws_size,
                              hipStream_t stream) {
    (void)in_sizes; (void)n_in; (void)out_size; (void)ws_size;
    const void* x    = d_in[0];
    const void* Wg_q = d_in[4];  const void* bg_q = d_in[5];
    const void* Wg_k = d_in[9];  const void* bg_k = d_in[10];
    const void* Wg_v = d_in[14]; const void* bg_v = d_in[15];

    char* ws = (char*)d_ws;
    int*    flag = (int*)ws;    ws += 16;
    float*  g9   = (float*)ws;  ws += (size_t)M_*9*4;            //   0.3 MB
    float*  part = (float*)ws;  ws += (size_t)B_*NCH_*D_*4;      //   0.26 MB
    ushort* Wt   = (ushort*)ws; ws += (size_t)K3_*K3_*2;         //  18 MB
    ushort* WoT  = (ushort*)ws; ws += (size_t)D_*D_*2;           //   2 MB
    ushort* Xc   = (ushort*)ws; ws += (size_t)M_*K3_*2;          //  50 MB (unscaled concat)
    ushort* QKV  = (ushort*)ws; ws += (size_t)M_*K3_*2;         //  50 MB
    ushort* AO   = (ushort*)ws; ws += (size_t)M_*D_*2;           //  17 MB  (total ~140 MB)

    detect_kernel<<<1, 256, 0, stream>>>((const ushort*)x, flag);
    gates_kernel<<<M_/4, 256, 0, stream>>>(x, Wg_q, bg_q, Wg_k, bg_k, Wg_v, bg_v, flag, g9);
    chunk_sum_kernel<<<dim3(D_/256, NCH_, B_), 256, 0, stream>>>(x, flag, part);
    scan_part_kernel<<<(B_*D_)/256, 256, 0, stream>>>(part);
    WPtrs wp;
    wp.w[0] = d_in[1];  wp.w[1] = d_in[2];  wp.w[2] = d_in[3];
    wp.w[3] = d_in[6];  wp.w[4] = d_in[7];  wp.w[5] = d_in[8];
    wp.w[6] = d_in[11]; wp.w[7] = d_in[12]; wp.w[8] = d_in[13];
    wp.w[9] = d_in[16];
    transpose_w_kernel<<<dim3(32, 32, 10), 256, 0, stream>>>(wp, flag, Wt, WoT);
    build_xs_kernel<<<dim3(D_/512, NCH_, B_), 256, 0, stream>>>(x, part, flag, Xc);
    // QKV: gated GEMM, M=8192, N=3072, K=3072; 32x12 = 384 blocks
    gemm_qkv_kernel<<<384, 512, 0, stream>>>(Xc, Wt, QKV, g9);
    attn_kernel<<<B_*T_, 256, 0, stream>>>(QKV, AO);
    // out = AO @ Wo : M=8192, N=1024, K=1024  (f32 out, ungated), 256 blocks
    gemm_bt8_kernel<float, 4, false><<<256, 512, 0, stream>>>(AO, WoT, (float*)d_out, nullptr, D_, D_, D_);
}

// Round 9
// 449.385 us; speedup vs baseline: 1.1886x; 1.1886x over previous
//
#include <hip/hip_runtime.h>
#include <hip/hip_bf16.h>
#include <cstdint>

#define B_   2
#define T_   4096
#define D_   1024
#define H_   16
#define DH_  64
#define M_   (B_*T_)     // 8192 rows
#define K3_  (3*D_)      // 3072
#define TC_  32          // cumsum chunk (32 -> 4x more blocks in P2/P4)
#define NCH_ (T_/TC_)    // 128 chunks

typedef __attribute__((ext_vector_type(4))) float  f32x4;
typedef __attribute__((ext_vector_type(8))) short  short8;

__device__ __forceinline__ float bf2f(ushort u) {
    union { uint32_t i; float f; } v; v.i = ((uint32_t)u) << 16; return v.f;
}
__device__ __forceinline__ ushort f2bf(float f) {
    union { float f; uint32_t i; } v; v.f = f;
    uint32_t r = v.i + 0x7FFF + ((v.i >> 16) & 1);
    return (ushort)(r >> 16);
}

template<bool F32>
__device__ __forceinline__ float ld_in(const void* p, size_t i) {
    if (F32) return ((const float*)p)[i];
    return bf2f(((const ushort*)p)[i]);
}
// 4-wide load: o[0..3] = in[i..i+3]
template<bool F32>
__device__ __forceinline__ void ld4_in(const void* p, size_t i, float* o) {
    if (F32) {
        float4 v = *(const float4*)((const float*)p + i);
        o[0] = v.x; o[1] = v.y; o[2] = v.z; o[3] = v.w;
    } else {
        ushort4 v = *(const ushort4*)((const ushort*)p + i);
        o[0] = bf2f(v.x); o[1] = bf2f(v.y); o[2] = bf2f(v.z); o[3] = bf2f(v.w);
    }
}

// store helpers: bf16 internal buffers vs f32 final output
__device__ __forceinline__ void st_c(ushort* p, float v) { *p = f2bf(v); }
__device__ __forceinline__ void st_c(float*  p, float v) { *p = v; }

#define GLOAD_LDS16(g, l) \
    __builtin_amdgcn_global_load_lds((const __attribute__((address_space(1))) void*)(g), \
                                     (__attribute__((address_space(3))) void*)(l), 16, 0, 0)

// ---------------- P0: dtype detector ----------------
__global__ void detect_kernel(const ushort* __restrict__ xu, int* __restrict__ flag) {
    __shared__ int cnt;
    if (threadIdx.x == 0) cnt = 0;
    __syncthreads();
    int c = 0;
    for (int i = threadIdx.x; i < 16384; i += 256) {
        ushort u = xu[i];
        if ((u & 0x7F80) == 0x7F80) c++;
    }
    if (c) atomicAdd(&cnt, c);
    __syncthreads();
    if (threadIdx.x == 0) flag[0] = (cnt > 0) ? 1 : 0;
}

// ---------------- P1: gates -> telescoping chain ratios ----------------
// g9[row][p*3+s] stores: s=0: g0/g1', s=1: g1'/g2', s=2: g2'  (g'=max(g,1e-30))
template<bool F32>
__device__ __forceinline__ void gates_body(const void* x,
                                           const void* Wg_q, const void* bg_q,
                                           const void* Wg_k, const void* bg_k,
                                           const void* Wg_v, const void* bg_v,
                                           float* __restrict__ g9) {
    const int wave = threadIdx.x >> 6, lane = threadIdx.x & 63;
    const int row  = blockIdx.x * 4 + wave;
    const size_t xoff = (size_t)row * D_;
    float acc[9] = {0,0,0,0,0,0,0,0,0};
    for (int d = lane; d < D_; d += 64) {
        float xv = ld_in<F32>(x, xoff + d);
        #pragma unroll
        for (int c = 0; c < 3; c++) {
            acc[0+c] += xv * ld_in<F32>(Wg_q, d*3+c);
            acc[3+c] += xv * ld_in<F32>(Wg_k, d*3+c);
            acc[6+c] += xv * ld_in<F32>(Wg_v, d*3+c);
        }
    }
    #pragma unroll
    for (int i = 0; i < 9; i++) {
        #pragma unroll
        for (int o = 32; o >= 1; o >>= 1) acc[i] += __shfl_xor(acc[i], o, 64);
    }
    const void* bgs[3] = {bg_q, bg_k, bg_v};
    float g[9];
    #pragma unroll
    for (int p = 0; p < 3; p++) {
        float l0 = acc[p*3+0] + ld_in<F32>(bgs[p], 0);
        float l1 = acc[p*3+1] + ld_in<F32>(bgs[p], 1);
        float l2 = acc[p*3+2] + ld_in<F32>(bgs[p], 2);
        float mx = fmaxf(l0, fmaxf(l1, l2));
        float e0 = expf(l0-mx), e1 = expf(l1-mx), e2 = expf(l2-mx);
        float s  = e0+e1+e2;
        float g0 = fminf(e0/s, 0.6f), g1 = fminf(e1/s, 0.6f), g2 = fminf(e2/s, 0.6f);
        float s2 = g0+g1+g2;
        g0 /= s2; g1 /= s2; g2 /= s2;
        float g1c = fmaxf(g1, 1e-30f), g2c = fmaxf(g2, 1e-30f);
        g[p*3+0] = g0 / g1c;
        g[p*3+1] = g1c / g2c;
        g[p*3+2] = g2c;
    }
    if (lane == 0) {
        #pragma unroll
        for (int i = 0; i < 9; i++) g9[(size_t)row*9 + i] = g[i];
    }
}
__global__ void gates_kernel(const void* x,
                             const void* Wg_q, const void* bg_q,
                             const void* Wg_k, const void* bg_k,
                             const void* Wg_v, const void* bg_v,
                             const int* __restrict__ flag, float* __restrict__ g9) {
    if (flag[0]) gates_body<true >(x, Wg_q, bg_q, Wg_k, bg_k, Wg_v, bg_v, g9);
    else         gates_body<false>(x, Wg_q, bg_q, Wg_k, bg_k, Wg_v, bg_v, g9);
}

// ---------------- P2: per-chunk sums (TC=32) ----------------
template<bool F32>
__device__ __forceinline__ void chunk_sum_body(const void* x, float* __restrict__ part) {
    const int d = blockIdx.x * 256 + threadIdx.x;
    const int tc = blockIdx.y, b = blockIdx.z;
    const size_t base = ((size_t)b*T_ + (size_t)tc*TC_) * D_ + d;
    float s = 0.f;
    for (int i = 0; i < TC_; i++) s += ld_in<F32>(x, base + (size_t)i * D_);
    part[((size_t)b*NCH_ + tc) * D_ + d] = s;
}
__global__ void chunk_sum_kernel(const void* x, const int* __restrict__ flag,
                                 float* __restrict__ part) {
    if (flag[0]) chunk_sum_body<true >(x, part);
    else         chunk_sum_body<false>(x, part);
}

// ---------------- P3: exclusive scan of chunk sums (128 chunks) ----------------
__global__ void scan_part_kernel(float* __restrict__ part) {
    const int idx = blockIdx.x * 256 + threadIdx.x;   // 0..2047
    const int b = idx >> 10, d = idx & (D_-1);
    float run = 0.f;
    for (int tc = 0; tc < NCH_; tc++) {
        size_t o = ((size_t)b*NCH_ + tc) * D_ + d;
        float v = part[o]; part[o] = run; run += v;
    }
}

// ---------------- P4: build UNSCALED concat Xc[row] = [x | integ | deriv] ----
// 4 columns/thread: float4/ushort4 reads, ushort4 (8B) stores.
// Grid (1, NCH_=128, B_) = 256 blocks x 256 thr -> all CUs busy (was 128 blks).
template<bool F32>
__device__ __forceinline__ void build_xs_body(const void* x, const float* __restrict__ part,
                                              ushort* __restrict__ Xc) {
    const int d0 = threadIdx.x * 4;                 // 0..1020
    const int tc = blockIdx.y, b = blockIdx.z;
    const int t0 = tc * TC_;
    float carry[4], prev[4];
    {
        float4 c4 = *(const float4*)&part[((size_t)b*NCH_ + tc) * D_ + d0];
        carry[0] = c4.x; carry[1] = c4.y; carry[2] = c4.z; carry[3] = c4.w;
    }
    const size_t xbase = ((size_t)b*T_ + t0) * D_ + d0;
    if (t0 > 0) ld4_in<F32>(x, xbase - D_, prev);
    else        { prev[0] = prev[1] = prev[2] = prev[3] = 0.f; }
    for (int i = 0; i < TC_; i++) {
        const int t = t0 + i;
        float xv[4];
        ld4_in<F32>(x, xbase + (size_t)i * D_, xv);
        const float rinv = 1.0f / (float)(t + 1);
        ushort4 ox, oi, od;
        {
            carry[0] += xv[0]; carry[1] += xv[1]; carry[2] += xv[2]; carry[3] += xv[3];
            ox = make_ushort4(f2bf(xv[0]), f2bf(xv[1]), f2bf(xv[2]), f2bf(xv[3]));
            oi = make_ushort4(f2bf(carry[0]*rinv), f2bf(carry[1]*rinv),
                              f2bf(carry[2]*rinv), f2bf(carry[3]*rinv));
            if (t == 0) od = make_ushort4(0, 0, 0, 0);
            else od = make_ushort4(f2bf(xv[0]-prev[0]), f2bf(xv[1]-prev[1]),
                                   f2bf(xv[2]-prev[2]), f2bf(xv[3]-prev[3]));
            prev[0] = xv[0]; prev[1] = xv[1]; prev[2] = xv[2]; prev[3] = xv[3];
        }
        const size_t base = ((size_t)b*T_ + t) * K3_ + d0;
        *(ushort4*)(Xc + base       ) = ox;
        *(ushort4*)(Xc + base +   D_) = oi;
        *(ushort4*)(Xc + base + 2*D_) = od;
    }
}
__global__ void build_xs_kernel(const void* x, const float* __restrict__ part,
                                const int* __restrict__ flag, ushort* __restrict__ Xc) {
    if (flag[0]) build_xs_body<true >(x, part, Xc);
    else         build_xs_body<false>(x, part, Xc);
}

// ---------------- P5: weight transpose -> (N,K) bf16 ----------------
struct WPtrs { const void* w[10]; };
template<bool F32>
__device__ __forceinline__ void transpose_w_body(WPtrs ptrs, ushort* __restrict__ Wt,
                                                 ushort* __restrict__ WoT) {
    const int z = blockIdx.z;                 // 0..8: W{p,j}; 9: Wo
    const void* src = ptrs.w[z];
    __shared__ float tile[32][33];
    const int tx = threadIdx.x & 31, ty = threadIdx.x >> 5;
    const int d0 = blockIdx.x * 32, c0 = blockIdx.y * 32;
    #pragma unroll
    for (int i = 0; i < 4; i++) {
        int r = ty + i*8;
        tile[r][tx] = ld_in<F32>(src, (size_t)(d0 + r) * D_ + c0 + tx);
    }
    __syncthreads();
    if (z < 9) {
        const int p = z / 3, j = z % 3;
        #pragma unroll
        for (int i = 0; i < 4; i++) {
            int r = ty + i*8;
            Wt[(size_t)(p*D_ + c0 + r) * K3_ + j*D_ + d0 + tx] = f2bf(tile[tx][r]);
        }
    } else {
        #pragma unroll
        for (int i = 0; i < 4; i++) {
            int r = ty + i*8;
            WoT[(size_t)(c0 + r) * D_ + d0 + tx] = f2bf(tile[tx][r]);
        }
    }
}
__global__ void transpose_w_kernel(WPtrs ptrs, const int* __restrict__ flag,
                                   ushort* __restrict__ Wt, ushort* __restrict__ WoT) {
    if (flag[0]) transpose_w_body<true >(ptrs, Wt, WoT);
    else         transpose_w_body<false>(ptrs, Wt, WoT);
}

// ---------------- GEMM (r1-proven): C(MxN) = A(MxK,row) * Bt(NxK,row)^T -----
// 128x256 tile, BK=64, 8 waves (2Mx4N, 64x64/wave), ring-of-3 LDS (144 KB),
// phase-interleaved m201 skeleton with COUNTED vmcnt (never drains to 0 in
// the main loop), s_setprio around MFMA clusters, XOR-swizzled staging.
// Measured (r1): 184.7us QKV, MfmaUtil 37.5%, 0 conflicts, no spill (VGPR 88).
template<typename CT, int NTILES, bool GATED>
__global__ __launch_bounds__(512, 2) void gemm_bt8_kernel(
        const ushort* __restrict__ Abase,
        const ushort* __restrict__ Bt,
        CT* __restrict__ C,
        const float* __restrict__ g9,
        int K, int lda, int ldc) {
    __shared__ __align__(16) ushort LDS[3 * 24576];
    const int tid  = threadIdx.x;
    const int lane = tid & 63;
    const int wave = tid >> 6;
    const int wm   = wave >> 2;
    const int wn   = wave & 3;
    const int quad = lane >> 4, l16 = lane & 15, sw = l16 & 7;

    const int MT     = M_ / 128;                 // 64
    const int cpx    = (MT * NTILES) / 8;
    const int wg     = (blockIdx.x % 8) * cpx + blockIdx.x / 8;
    const int mchunk = MT / 8;                   // 8
    const int rem    = wg % (mchunk * NTILES);
    const int mt     = (wg / (mchunk * NTILES)) * mchunk + (rem % mchunk);
    const int nt     = rem / mchunk;
    const int m0 = mt * 128;
    const int n0 = nt * 256;
    const int p  = n0 >> 10;

    const ushort* asrc[2]; int aoff[2];
    #pragma unroll
    for (int g = 0; g < 2; g++) {
        const int I = g*512 + tid;
        const int row = I >> 3, c8 = (I & 7) ^ (row & 7);
        asrc[g] = Abase + (size_t)(m0 + row) * lda + c8*8;
        aoff[g] = I * 8;
    }
    const ushort* bsrc[4]; int boff[4];
    #pragma unroll
    for (int g = 0; g < 4; g++) {
        const int I = g*512 + tid;
        const int row = I >> 3, c8 = (I & 7) ^ (row & 7);
        bsrc[g] = Bt + (size_t)(n0 + row) * K + c8*8;
        boff[g] = I * 8;
    }
    int ard[4], brd[4];
    #pragma unroll
    for (int i = 0; i < 4; i++) {
        ard[i] = (wm*64 + i*16 + l16) * 64;
        brd[i] = (wn*64 + i*16 + l16) * 64;
    }

    const int NKT = K >> 6;
    f32x4 acc[4][4] = {};

    #pragma unroll
    for (int g = 0; g < 2; g++) GLOAD_LDS16(asrc[g], &LDS[aoff[g]]);
    #pragma unroll
    for (int g = 0; g < 4; g++) GLOAD_LDS16(bsrc[g], &LDS[8192 + boff[g]]);
    #pragma unroll
    for (int g = 0; g < 2; g++) GLOAD_LDS16(asrc[g] + 64, &LDS[24576 + aoff[g]]);
    #pragma unroll
    for (int g = 0; g < 4; g++) GLOAD_LDS16(bsrc[g] + 64, &LDS[24576 + 8192 + boff[g]]);
    asm volatile("s_waitcnt vmcnt(6)" ::: "memory");
    __builtin_amdgcn_s_barrier();

    for (int t = 0; t < NKT; ++t) {
        const int cur = t % 3;
        const int ab  = cur * 24576;
        const int bb  = ab + 8192;
        const bool do_stage = (t + 2 < NKT);
        const int sb  = ((t + 2) % 3) * 24576;
        const int skt = (t + 2) << 6;

        short8 af[4], bfr[4];

        #pragma unroll
        for (int i = 0; i < 4; i++)
            af[i]  = *(const short8*)&LDS[ab + ard[i] + (quad ^ sw) * 8];
        #pragma unroll
        for (int j = 0; j < 4; j++)
            bfr[j] = *(const short8*)&LDS[bb + brd[j] + (quad ^ sw) * 8];
        if (do_stage) {
            GLOAD_LDS16(asrc[0] + skt, &LDS[sb + aoff[0]]);
            GLOAD_LDS16(asrc[1] + skt, &LDS[sb + aoff[1]]);
            GLOAD_LDS16(bsrc[0] + skt, &LDS[sb + 8192 + boff[0]]);
        }
        __builtin_amdgcn_s_barrier();
        asm volatile("s_waitcnt lgkmcnt(0)" ::: "memory");
        __builtin_amdgcn_sched_barrier(0);
        __builtin_amdgcn_s_setprio(1);
        #pragma unroll
        for (int i = 0; i < 4; i++)
            #pragma unroll
            for (int j = 0; j < 4; j++)
                acc[i][j] = __builtin_amdgcn_mfma_f32_16x16x32_bf16(af[i], bfr[j], acc[i][j], 0, 0, 0);
        __builtin_amdgcn_s_setprio(0);
        __builtin_amdgcn_s_barrier();

        #pragma unroll
        for (int i = 0; i < 4; i++)
            af[i]  = *(const short8*)&LDS[ab + ard[i] + ((quad + 4) ^ sw) * 8];
        #pragma unroll
        for (int j = 0; j < 4; j++)
            bfr[j] = *(const short8*)&LDS[bb + brd[j] + ((quad + 4) ^ sw) * 8];
        if (do_stage) {
            GLOAD_LDS16(bsrc[1] + skt, &LDS[sb + 8192 + boff[1]]);
            GLOAD_LDS16(bsrc[2] + skt, &LDS[sb + 8192 + boff[2]]);
            GLOAD_LDS16(bsrc[3] + skt, &LDS[sb + 8192 + boff[3]]);
        }
        __builtin_amdgcn_s_barrier();
        asm volatile("s_waitcnt lgkmcnt(0)" ::: "memory");
        __builtin_amdgcn_sched_barrier(0);
        __builtin_amdgcn_s_setprio(1);
        #pragma unroll
        for (int i = 0; i < 4; i++)
            #pragma unroll
            for (int j = 0; j < 4; j++)
                acc[i][j] = __builtin_amdgcn_mfma_f32_16x16x32_bf16(af[i], bfr[j], acc[i][j], 0, 0, 0);
        __builtin_amdgcn_s_setprio(0);
        if (do_stage)          asm volatile("s_waitcnt vmcnt(6)" ::: "memory");
        else if (t + 1 < NKT)  asm volatile("s_waitcnt vmcnt(0)" ::: "memory");
        __builtin_amdgcn_s_barrier();

        if (GATED && ((t & 15) == 15)) {
            const int seg = t >> 4;
            #pragma unroll
            for (int i = 0; i < 4; i++) {
                float gv[4];
                #pragma unroll
                for (int rg = 0; rg < 4; rg++) {
                    const int rrow = m0 + wm*64 + i*16 + quad*4 + rg;
                    gv[rg] = g9[(size_t)rrow * 9 + p*3 + seg];
                }
                #pragma unroll
                for (int j = 0; j < 4; j++)
                    #pragma unroll
                    for (int rg = 0; rg < 4; rg++)
                        acc[i][j][rg] *= gv[rg];
            }
        }
    }

    #pragma unroll
    for (int i = 0; i < 4; i++) {
        #pragma unroll
        for (int j = 0; j < 4; j++) {
            const int rrow = m0 + wm*64 + i*16 + quad*4;
            const int col  = n0 + wn*64 + j*16 + l16;
            #pragma unroll
            for (int rg = 0; rg < 4; rg++)
                st_c(&C[(size_t)(rrow + rg) * ldc + col], acc[i][j][rg]);
        }
    }
}

// ---------------- attention: 128 threads x 8 elems (16B loads/stores) --------
// One block per (b,t); head = tid/8 (DH=64 = 8 lanes x 8 elems);
// dot-reduce = 3 shfl_xor over the 8-lane group. Math identical to the
// 256x4 version; half the waves, 16B/lane at the coalescing sweet spot.
__global__ __launch_bounds__(128) void attn_kernel(const ushort* __restrict__ QKV,
                                                   ushort* __restrict__ AO) {
    const int tid = threadIdx.x;
    const int bt  = blockIdx.x;              // b*T_ + t
    const int t   = bt & (T_-1);
    const size_t qrow = (size_t)bt * K3_;
    const int e0 = tid * 8;

    const short8 q8 = *(const short8*)(QKV + qrow + e0);
    float qf[8];
    #pragma unroll
    for (int j = 0; j < 8; j++) qf[j] = bf2f((ushort)q8[j]);

    float sc[14];
    #pragma unroll
    for (int a = 0; a < 14; a++) {
        const int off = (a <= 3) ? a : (1 << (a - 2));
        float pv = -1e30f;
        if (off <= t) {                      // block-uniform
            const short8 k8 = *(const short8*)(QKV + qrow - (size_t)off*K3_ + D_ + e0);
            float pp = 0.f;
            #pragma unroll
            for (int j = 0; j < 8; j++) pp += qf[j] * bf2f((ushort)k8[j]);
            pp += __shfl_xor(pp, 1, 64);
            pp += __shfl_xor(pp, 2, 64);
            pp += __shfl_xor(pp, 4, 64);
            pv = pp * 0.125f;                // DH^-0.5
        }
        sc[a] = pv;
    }
    float mx = -1e30f;
    #pragma unroll
    for (int a = 0; a < 14; a++) mx = fmaxf(mx, sc[a]);
    float ev[14], s = 0.0f;
    #pragma unroll
    for (int a = 0; a < 14; a++) { ev[a] = (sc[a] > -1e29f) ? expf(sc[a] - mx) : 0.0f; s += ev[a]; }
    const float rs = 1.0f / s;

    float ao[8] = {0,0,0,0,0,0,0,0};
    #pragma unroll
    for (int a = 0; a < 14; a++) {
        const int off = (a <= 3) ? a : (1 << (a - 2));
        if (off <= t) {
            const short8 v8 = *(const short8*)(QKV + qrow - (size_t)off*K3_ + 2*D_ + e0);
            const float w = ev[a] * rs;
            #pragma unroll
            for (int j = 0; j < 8; j++) ao[j] += w * bf2f((ushort)v8[j]);
        }
    }
    short8 o8;
    #pragma unroll
    for (int j = 0; j < 8; j++) o8[j] = (short)f2bf(ao[j]);
    *(short8*)(AO + (size_t)bt * D_ + e0) = o8;
}

extern "C" void kernel_launch(void* const* d_in, const int* in_sizes, int n_in,
                              void* d_out, int out_size, void* d_ws, size_t ws_size,
                              hipStream_t stream) {
    (void)in_sizes; (void)n_in; (void)out_size; (void)ws_size;
    const void* x    = d_in[0];
    const void* Wg_q = d_in[4];  const void* bg_q = d_in[5];
    const void* Wg_k = d_in[9];  const void* bg_k = d_in[10];
    const void* Wg_v = d_in[14]; const void* bg_v = d_in[15];

    char* ws = (char*)d_ws;
    int*    flag = (int*)ws;    ws += 16;
    float*  g9   = (float*)ws;  ws += (size_t)M_*9*4;            //   0.3 MB
    float*  part = (float*)ws;  ws += (size_t)B_*NCH_*D_*4;      //   1.0 MB
    ushort* Wt   = (ushort*)ws; ws += (size_t)K3_*K3_*2;         //  18 MB
    ushort* WoT  = (ushort*)ws; ws += (size_t)D_*D_*2;           //   2 MB
    ushort* Xc   = (ushort*)ws; ws += (size_t)M_*K3_*2;          //  50 MB (unscaled concat)
    ushort* QKV  = (ushort*)ws; ws += (size_t)M_*K3_*2;          //  50 MB
    ushort* AO   = (ushort*)ws; ws += (size_t)M_*D_*2;           //  17 MB  (total ~141 MB)

    detect_kernel<<<1, 256, 0, stream>>>((const ushort*)x, flag);
    gates_kernel<<<M_/4, 256, 0, stream>>>(x, Wg_q, bg_q, Wg_k, bg_k, Wg_v, bg_v, flag, g9);
    chunk_sum_kernel<<<dim3(D_/256, NCH_, B_), 256, 0, stream>>>(x, flag, part);
    scan_part_kernel<<<(B_*D_)/256, 256, 0, stream>>>(part);
    WPtrs wp;
    wp.w[0] = d_in[1];  wp.w[1] = d_in[2];  wp.w[2] = d_in[3];
    wp.w[3] = d_in[6];  wp.w[4] = d_in[7];  wp.w[5] = d_in[8];
    wp.w[6] = d_in[11]; wp.w[7] = d_in[12]; wp.w[8] = d_in[13];
    wp.w[9] = d_in[16];
    transpose_w_kernel<<<dim3(32, 32, 10), 256, 0, stream>>>(wp, flag, Wt, WoT);
    build_xs_kernel<<<dim3(1, NCH_, B_), 256, 0, stream>>>(x, part, flag, Xc);
    // QKV: gated GEMM, M=8192, N=3072 (3 proj x 1024), K=3072 in 3 segments
    // grid = 64 mtiles x 12 ntiles = 768 blocks = exactly 3 device-waves
    gemm_bt8_kernel<ushort, 12, true><<<768, 512, 0, stream>>>(Xc, Wt, QKV, g9, K3_, K3_, K3_);
    attn_kernel<<<B_*T_, 128, 0, stream>>>(QKV, AO);
    // out = AO @ Wo : M=8192, N=1024, K=1024  (f32 out, ungated), 256 blocks
    gemm_bt8_kernel<float, 4, false><<<256, 512, 0, stream>>>(AO, WoT, (float*)d_out, nullptr, D_, D_, D_);
}

// Round 10
// 437.498 us; speedup vs baseline: 1.2209x; 1.0272x over previous
//
#include <hip/hip_runtime.h>
#include <hip/hip_bf16.h>
#include <cstdint>

#define B_   2
#define T_   4096
#define D_   1024
#define H_   16
#define DH_  64
#define M_   (B_*T_)     // 8192 rows
#define K3_  (3*D_)      // 3072
#define TC_  32          // cumsum chunk
#define NCH_ (T_/TC_)    // 128 chunks

typedef __attribute__((ext_vector_type(4))) float  f32x4;
typedef __attribute__((ext_vector_type(8))) short  short8;

__device__ __forceinline__ float bf2f(ushort u) {
    union { uint32_t i; float f; } v; v.i = ((uint32_t)u) << 16; return v.f;
}
__device__ __forceinline__ ushort f2bf(float f) {
    union { float f; uint32_t i; } v; v.f = f;
    uint32_t r = v.i + 0x7FFF + ((v.i >> 16) & 1);
    return (ushort)(r >> 16);
}

template<bool F32>
__device__ __forceinline__ float ld_in(const void* p, size_t i) {
    if (F32) return ((const float*)p)[i];
    return bf2f(((const ushort*)p)[i]);
}
// 4-wide load: o[0..3] = in[i..i+3]
template<bool F32>
__device__ __forceinline__ void ld4_in(const void* p, size_t i, float* o) {
    if (F32) {
        float4 v = *(const float4*)((const float*)p + i);
        o[0] = v.x; o[1] = v.y; o[2] = v.z; o[3] = v.w;
    } else {
        ushort4 v = *(const ushort4*)((const ushort*)p + i);
        o[0] = bf2f(v.x); o[1] = bf2f(v.y); o[2] = bf2f(v.z); o[3] = bf2f(v.w);
    }
}

// store helpers: bf16 internal buffers vs f32 final output
__device__ __forceinline__ void st_c(ushort* p, float v) { *p = f2bf(v); }
__device__ __forceinline__ void st_c(float*  p, float v) { *p = v; }

#define GLOAD_LDS16(g, l) \
    __builtin_amdgcn_global_load_lds((const __attribute__((address_space(1))) void*)(g), \
                                     (__attribute__((address_space(3))) void*)(l), 16, 0, 0)

// ---------------- P0: dtype detector ----------------
__global__ void detect_kernel(const ushort* __restrict__ xu, int* __restrict__ flag) {
    __shared__ int cnt;
    if (threadIdx.x == 0) cnt = 0;
    __syncthreads();
    int c = 0;
    for (int i = threadIdx.x; i < 16384; i += 256) {
        ushort u = xu[i];
        if ((u & 0x7F80) == 0x7F80) c++;
    }
    if (c) atomicAdd(&cnt, c);
    __syncthreads();
    if (threadIdx.x == 0) flag[0] = (cnt > 0) ? 1 : 0;
}

// ---------------- P1: gates -> telescoping chain ratios ----------------
// g9[row][p*3+s] stores: s=0: g0/g1', s=1: g1'/g2', s=2: g2'  (g'=max(g,1e-30))
// r10: vectorized — x via float4/ushort4 (4 iters, was 16 scalar), weights via
// 3x 4-wide loads per matrix per iter (was 36 scalar) [G13].
template<bool F32>
__device__ __forceinline__ void gates_body(const void* x,
                                           const void* Wg_q, const void* bg_q,
                                           const void* Wg_k, const void* bg_k,
                                           const void* Wg_v, const void* bg_v,
                                           float* __restrict__ g9) {
    const int wave = threadIdx.x >> 6, lane = threadIdx.x & 63;
    const int row  = blockIdx.x * 4 + wave;
    const size_t xoff = (size_t)row * D_;
    float acc[9] = {0,0,0,0,0,0,0,0,0};
    for (int d0 = lane * 4; d0 < D_; d0 += 256) {   // 4 iterations
        float xv[4], wq[12], wk[12], wv[12];
        ld4_in<F32>(x, xoff + d0, xv);
        #pragma unroll
        for (int q = 0; q < 3; q++) {
            ld4_in<F32>(Wg_q, (size_t)d0*3 + q*4, wq + q*4);
            ld4_in<F32>(Wg_k, (size_t)d0*3 + q*4, wk + q*4);
            ld4_in<F32>(Wg_v, (size_t)d0*3 + q*4, wv + q*4);
        }
        #pragma unroll
        for (int e = 0; e < 4; e++)
            #pragma unroll
            for (int c = 0; c < 3; c++) {
                acc[0+c] += xv[e] * wq[e*3+c];
                acc[3+c] += xv[e] * wk[e*3+c];
                acc[6+c] += xv[e] * wv[e*3+c];
            }
    }
    #pragma unroll
    for (int i = 0; i < 9; i++) {
        #pragma unroll
        for (int o = 32; o >= 1; o >>= 1) acc[i] += __shfl_xor(acc[i], o, 64);
    }
    const void* bgs[3] = {bg_q, bg_k, bg_v};
    float g[9];
    #pragma unroll
    for (int p = 0; p < 3; p++) {
        float l0 = acc[p*3+0] + ld_in<F32>(bgs[p], 0);
        float l1 = acc[p*3+1] + ld_in<F32>(bgs[p], 1);
        float l2 = acc[p*3+2] + ld_in<F32>(bgs[p], 2);
        float mx = fmaxf(l0, fmaxf(l1, l2));
        float e0 = expf(l0-mx), e1 = expf(l1-mx), e2 = expf(l2-mx);
        float s  = e0+e1+e2;
        float g0 = fminf(e0/s, 0.6f), g1 = fminf(e1/s, 0.6f), g2 = fminf(e2/s, 0.6f);
        float s2 = g0+g1+g2;
        g0 /= s2; g1 /= s2; g2 /= s2;
        float g1c = fmaxf(g1, 1e-30f), g2c = fmaxf(g2, 1e-30f);
        g[p*3+0] = g0 / g1c;
        g[p*3+1] = g1c / g2c;
        g[p*3+2] = g2c;
    }
    if (lane == 0) {
        #pragma unroll
        for (int i = 0; i < 9; i++) g9[(size_t)row*9 + i] = g[i];
    }
}
__global__ void gates_kernel(const void* x,
                             const void* Wg_q, const void* bg_q,
                             const void* Wg_k, const void* bg_k,
                             const void* Wg_v, const void* bg_v,
                             const int* __restrict__ flag, float* __restrict__ g9) {
    if (flag[0]) gates_body<true >(x, Wg_q, bg_q, Wg_k, bg_k, Wg_v, bg_v, g9);
    else         gates_body<false>(x, Wg_q, bg_q, Wg_k, bg_k, Wg_v, bg_v, g9);
}

// ---------------- P2: per-chunk sums (TC=32) ----------------
template<bool F32>
__device__ __forceinline__ void chunk_sum_body(const void* x, float* __restrict__ part) {
    const int d = blockIdx.x * 256 + threadIdx.x;
    const int tc = blockIdx.y, b = blockIdx.z;
    const size_t base = ((size_t)b*T_ + (size_t)tc*TC_) * D_ + d;
    float s = 0.f;
    for (int i = 0; i < TC_; i++) s += ld_in<F32>(x, base + (size_t)i * D_);
    part[((size_t)b*NCH_ + tc) * D_ + d] = s;
}
__global__ void chunk_sum_kernel(const void* x, const int* __restrict__ flag,
                                 float* __restrict__ part) {
    if (flag[0]) chunk_sum_body<true >(x, part);
    else         chunk_sum_body<false>(x, part);
}

// ---------------- P3: exclusive scan of chunk sums ----------------
// r10: grid 32 blocks x 64 threads (was 8 x 256): 4x the CUs on the same
// 2048 independent column-chains — latency-bound, parallelism-starved before.
__global__ void scan_part_kernel(float* __restrict__ part) {
    const int idx = blockIdx.x * 64 + threadIdx.x;    // 0..2047
    const int b = idx >> 10, d = idx & (D_-1);
    float run = 0.f;
    for (int tc = 0; tc < NCH_; tc++) {
        size_t o = ((size_t)b*NCH_ + tc) * D_ + d;
        float v = part[o]; part[o] = run; run += v;
    }
}

// ---------------- P4: build UNSCALED concat Xc[row] = [x | integ | deriv] ----
template<bool F32>
__device__ __forceinline__ void build_xs_body(const void* x, const float* __restrict__ part,
                                              ushort* __restrict__ Xc) {
    const int d0 = threadIdx.x * 4;                 // 0..1020
    const int tc = blockIdx.y, b = blockIdx.z;
    const int t0 = tc * TC_;
    float carry[4], prev[4];
    {
        float4 c4 = *(const float4*)&part[((size_t)b*NCH_ + tc) * D_ + d0];
        carry[0] = c4.x; carry[1] = c4.y; carry[2] = c4.z; carry[3] = c4.w;
    }
    const size_t xbase = ((size_t)b*T_ + t0) * D_ + d0;
    if (t0 > 0) ld4_in<F32>(x, xbase - D_, prev);
    else        { prev[0] = prev[1] = prev[2] = prev[3] = 0.f; }
    for (int i = 0; i < TC_; i++) {
        const int t = t0 + i;
        float xv[4];
        ld4_in<F32>(x, xbase + (size_t)i * D_, xv);
        const float rinv = 1.0f / (float)(t + 1);
        ushort4 ox, oi, od;
        {
            carry[0] += xv[0]; carry[1] += xv[1]; carry[2] += xv[2]; carry[3] += xv[3];
            ox = make_ushort4(f2bf(xv[0]), f2bf(xv[1]), f2bf(xv[2]), f2bf(xv[3]));
            oi = make_ushort4(f2bf(carry[0]*rinv), f2bf(carry[1]*rinv),
                              f2bf(carry[2]*rinv), f2bf(carry[3]*rinv));
            if (t == 0) od = make_ushort4(0, 0, 0, 0);
            else od = make_ushort4(f2bf(xv[0]-prev[0]), f2bf(xv[1]-prev[1]),
                                   f2bf(xv[2]-prev[2]), f2bf(xv[3]-prev[3]));
            prev[0] = xv[0]; prev[1] = xv[1]; prev[2] = xv[2]; prev[3] = xv[3];
        }
        const size_t base = ((size_t)b*T_ + t) * K3_ + d0;
        *(ushort4*)(Xc + base       ) = ox;
        *(ushort4*)(Xc + base +   D_) = oi;
        *(ushort4*)(Xc + base + 2*D_) = od;
    }
}
__global__ void build_xs_kernel(const void* x, const float* __restrict__ part,
                                const int* __restrict__ flag, ushort* __restrict__ Xc) {
    if (flag[0]) build_xs_body<true >(x, part, Xc);
    else         build_xs_body<false>(x, part, Xc);
}

// ---------------- P5: weight transpose -> (N,K) bf16 ----------------
struct WPtrs { const void* w[10]; };
template<bool F32>
__device__ __forceinline__ void transpose_w_body(WPtrs ptrs, ushort* __restrict__ Wt,
                                                 ushort* __restrict__ WoT) {
    const int z = blockIdx.z;                 // 0..8: W{p,j}; 9: Wo
    const void* src = ptrs.w[z];
    __shared__ float tile[32][33];
    const int tx = threadIdx.x & 31, ty = threadIdx.x >> 5;
    const int d0 = blockIdx.x * 32, c0 = blockIdx.y * 32;
    #pragma unroll
    for (int i = 0; i < 4; i++) {
        int r = ty + i*8;
        tile[r][tx] = ld_in<F32>(src, (size_t)(d0 + r) * D_ + c0 + tx);
    }
    __syncthreads();
    if (z < 9) {
        const int p = z / 3, j = z % 3;
        #pragma unroll
        for (int i = 0; i < 4; i++) {
            int r = ty + i*8;
            Wt[(size_t)(p*D_ + c0 + r) * K3_ + j*D_ + d0 + tx] = f2bf(tile[tx][r]);
        }
    } else {
        #pragma unroll
        for (int i = 0; i < 4; i++) {
            int r = ty + i*8;
            WoT[(size_t)(c0 + r) * D_ + d0 + tx] = f2bf(tile[tx][r]);
        }
    }
}
__global__ void transpose_w_kernel(WPtrs ptrs, const int* __restrict__ flag,
                                   ushort* __restrict__ Wt, ushort* __restrict__ WoT) {
    if (flag[0]) transpose_w_body<true >(ptrs, Wt, WoT);
    else         transpose_w_body<false>(ptrs, Wt, WoT);
}

// ---------------- GEMM (r1-proven): C(MxN) = A(MxK,row) * Bt(NxK,row)^T -----
// 128x256 tile, BK=64, 8 waves (2Mx4N, 64x64/wave), ring-of-3 LDS (144 KB),
// phase-interleaved m201 skeleton with COUNTED vmcnt, s_setprio, XOR-swizzle.
// Measured: 184us QKV, MfmaUtil 36.8%, 0 conflicts, no spill (VGPR 88).
template<typename CT, int NTILES, bool GATED>
__global__ __launch_bounds__(512, 2) void gemm_bt8_kernel(
        const ushort* __restrict__ Abase,
        const ushort* __restrict__ Bt,
        CT* __restrict__ C,
        const float* __restrict__ g9,
        int K, int lda, int ldc) {
    __shared__ __align__(16) ushort LDS[3 * 24576];
    const int tid  = threadIdx.x;
    const int lane = tid & 63;
    const int wave = tid >> 6;
    const int wm   = wave >> 2;
    const int wn   = wave & 3;
    const int quad = lane >> 4, l16 = lane & 15, sw = l16 & 7;

    const int MT     = M_ / 128;                 // 64
    const int cpx    = (MT * NTILES) / 8;
    const int wg     = (blockIdx.x % 8) * cpx + blockIdx.x / 8;
    const int mchunk = MT / 8;                   // 8
    const int rem    = wg % (mchunk * NTILES);
    const int mt     = (wg / (mchunk * NTILES)) * mchunk + (rem % mchunk);
    const int nt     = rem / mchunk;
    const int m0 = mt * 128;
    const int n0 = nt * 256;
    const int p  = n0 >> 10;

    const ushort* asrc[2]; int aoff[2];
    #pragma unroll
    for (int g = 0; g < 2; g++) {
        const int I = g*512 + tid;
        const int row = I >> 3, c8 = (I & 7) ^ (row & 7);
        asrc[g] = Abase + (size_t)(m0 + row) * lda + c8*8;
        aoff[g] = I * 8;
    }
    const ushort* bsrc[4]; int boff[4];
    #pragma unroll
    for (int g = 0; g < 4; g++) {
        const int I = g*512 + tid;
        const int row = I >> 3, c8 = (I & 7) ^ (row & 7);
        bsrc[g] = Bt + (size_t)(n0 + row) * K + c8*8;
        boff[g] = I * 8;
    }
    int ard[4], brd[4];
    #pragma unroll
    for (int i = 0; i < 4; i++) {
        ard[i] = (wm*64 + i*16 + l16) * 64;
        brd[i] = (wn*64 + i*16 + l16) * 64;
    }

    const int NKT = K >> 6;
    f32x4 acc[4][4] = {};

    #pragma unroll
    for (int g = 0; g < 2; g++) GLOAD_LDS16(asrc[g], &LDS[aoff[g]]);
    #pragma unroll
    for (int g = 0; g < 4; g++) GLOAD_LDS16(bsrc[g], &LDS[8192 + boff[g]]);
    #pragma unroll
    for (int g = 0; g < 2; g++) GLOAD_LDS16(asrc[g] + 64, &LDS[24576 + aoff[g]]);
    #pragma unroll
    for (int g = 0; g < 4; g++) GLOAD_LDS16(bsrc[g] + 64, &LDS[24576 + 8192 + boff[g]]);
    asm volatile("s_waitcnt vmcnt(6)" ::: "memory");
    __builtin_amdgcn_s_barrier();

    for (int t = 0; t < NKT; ++t) {
        const int cur = t % 3;
        const int ab  = cur * 24576;
        const int bb  = ab + 8192;
        const bool do_stage = (t + 2 < NKT);
        const int sb  = ((t + 2) % 3) * 24576;
        const int skt = (t + 2) << 6;

        short8 af[4], bfr[4];

        #pragma unroll
        for (int i = 0; i < 4; i++)
            af[i]  = *(const short8*)&LDS[ab + ard[i] + (quad ^ sw) * 8];
        #pragma unroll
        for (int j = 0; j < 4; j++)
            bfr[j] = *(const short8*)&LDS[bb + brd[j] + (quad ^ sw) * 8];
        if (do_stage) {
            GLOAD_LDS16(asrc[0] + skt, &LDS[sb + aoff[0]]);
            GLOAD_LDS16(asrc[1] + skt, &LDS[sb + aoff[1]]);
            GLOAD_LDS16(bsrc[0] + skt, &LDS[sb + 8192 + boff[0]]);
        }
        __builtin_amdgcn_s_barrier();
        asm volatile("s_waitcnt lgkmcnt(0)" ::: "memory");
        __builtin_amdgcn_sched_barrier(0);
        __builtin_amdgcn_s_setprio(1);
        #pragma unroll
        for (int i = 0; i < 4; i++)
            #pragma unroll
            for (int j = 0; j < 4; j++)
                acc[i][j] = __builtin_amdgcn_mfma_f32_16x16x32_bf16(af[i], bfr[j], acc[i][j], 0, 0, 0);
        __builtin_amdgcn_s_setprio(0);
        __builtin_amdgcn_s_barrier();

        #pragma unroll
        for (int i = 0; i < 4; i++)
            af[i]  = *(const short8*)&LDS[ab + ard[i] + ((quad + 4) ^ sw) * 8];
        #pragma unroll
        for (int j = 0; j < 4; j++)
            bfr[j] = *(const short8*)&LDS[bb + brd[j] + ((quad + 4) ^ sw) * 8];
        if (do_stage) {
            GLOAD_LDS16(bsrc[1] + skt, &LDS[sb + 8192 + boff[1]]);
            GLOAD_LDS16(bsrc[2] + skt, &LDS[sb + 8192 + boff[2]]);
            GLOAD_LDS16(bsrc[3] + skt, &LDS[sb + 8192 + boff[3]]);
        }
        __builtin_amdgcn_s_barrier();
        asm volatile("s_waitcnt lgkmcnt(0)" ::: "memory");
        __builtin_amdgcn_sched_barrier(0);
        __builtin_amdgcn_s_setprio(1);
        #pragma unroll
        for (int i = 0; i < 4; i++)
            #pragma unroll
            for (int j = 0; j < 4; j++)
                acc[i][j] = __builtin_amdgcn_mfma_f32_16x16x32_bf16(af[i], bfr[j], acc[i][j], 0, 0, 0);
        __builtin_amdgcn_s_setprio(0);
        if (do_stage)          asm volatile("s_waitcnt vmcnt(6)" ::: "memory");
        else if (t + 1 < NKT)  asm volatile("s_waitcnt vmcnt(0)" ::: "memory");
        __builtin_amdgcn_s_barrier();

        if (GATED && ((t & 15) == 15)) {
            const int seg = t >> 4;
            #pragma unroll
            for (int i = 0; i < 4; i++) {
                float gv[4];
                #pragma unroll
                for (int rg = 0; rg < 4; rg++) {
                    const int rrow = m0 + wm*64 + i*16 + quad*4 + rg;
                    gv[rg] = g9[(size_t)rrow * 9 + p*3 + seg];
                }
                #pragma unroll
                for (int j = 0; j < 4; j++)
                    #pragma unroll
                    for (int rg = 0; rg < 4; rg++)
                        acc[i][j][rg] *= gv[rg];
            }
        }
    }

    #pragma unroll
    for (int i = 0; i < 4; i++) {
        #pragma unroll
        for (int j = 0; j < 4; j++) {
            const int rrow = m0 + wm*64 + i*16 + quad*4;
            const int col  = n0 + wn*64 + j*16 + l16;
            #pragma unroll
            for (int rg = 0; rg < 4; rg++)
                st_c(&C[(size_t)(rrow + rg) * ldc + col], acc[i][j][rg]);
        }
    }
}

// ---------------- attention: 128 threads x 8 elems, XCD-contiguous blocks ----
// r10: bt remap (bi&7)*1024 + (bi>>3) — block i lands on XCD i%8, so XCD k
// owns the contiguous range bt in [1024k, 1024k+1024). 13/14 K/V offsets are
// <=512 rows -> the reused rows now live in the XCD's OWN L2 (4MB ~ working
// set) instead of bouncing through L3 under round-robin placement. Bijective.
__global__ __launch_bounds__(128) void attn_kernel(const ushort* __restrict__ QKV,
                                                   ushort* __restrict__ AO) {
    const int tid = threadIdx.x;
    const int bi  = blockIdx.x;
    const int bt  = (bi & 7) * 1024 + (bi >> 3);   // b*T_ + t, XCD-contiguous
    const int t   = bt & (T_-1);
    const size_t qrow = (size_t)bt * K3_;
    const int e0 = tid * 8;

    const short8 q8 = *(const short8*)(QKV + qrow + e0);
    float qf[8];
    #pragma unroll
    for (int j = 0; j < 8; j++) qf[j] = bf2f((ushort)q8[j]);

    float sc[14];
    #pragma unroll
    for (int a = 0; a < 14; a++) {
        const int off = (a <= 3) ? a : (1 << (a - 2));
        float pv = -1e30f;
        if (off <= t) {                      // block-uniform
            const short8 k8 = *(const short8*)(QKV + qrow - (size_t)off*K3_ + D_ + e0);
            float pp = 0.f;
            #pragma unroll
            for (int j = 0; j < 8; j++) pp += qf[j] * bf2f((ushort)k8[j]);
            pp += __shfl_xor(pp, 1, 64);
            pp += __shfl_xor(pp, 2, 64);
            pp += __shfl_xor(pp, 4, 64);
            pv = pp * 0.125f;                // DH^-0.5
        }
        sc[a] = pv;
    }
    float mx = -1e30f;
    #pragma unroll
    for (int a = 0; a < 14; a++) mx = fmaxf(mx, sc[a]);
    float ev[14], s = 0.0f;
    #pragma unroll
    for (int a = 0; a < 14; a++) { ev[a] = (sc[a] > -1e29f) ? expf(sc[a] - mx) : 0.0f; s += ev[a]; }
    const float rs = 1.0f / s;

    float ao[8] = {0,0,0,0,0,0,0,0};
    #pragma unroll
    for (int a = 0; a < 14; a++) {
        const int off = (a <= 3) ? a : (1 << (a - 2));
        if (off <= t) {
            const short8 v8 = *(const short8*)(QKV + qrow - (size_t)off*K3_ + 2*D_ + e0);
            const float w = ev[a] * rs;
            #pragma unroll
            for (int j = 0; j < 8; j++) ao[j] += w * bf2f((ushort)v8[j]);
        }
    }
    short8 o8;
    #pragma unroll
    for (int j = 0; j < 8; j++) o8[j] = (short)f2bf(ao[j]);
    *(short8*)(AO + (size_t)bt * D_ + e0) = o8;
}

extern "C" void kernel_launch(void* const* d_in, const int* in_sizes, int n_in,
                              void* d_out, int out_size, void* d_ws, size_t ws_size,
                              hipStream_t stream) {
    (void)in_sizes; (void)n_in; (void)out_size; (void)ws_size;
    const void* x    = d_in[0];
    const void* Wg_q = d_in[4];  const void* bg_q = d_in[5];
    const void* Wg_k = d_in[9];  const void* bg_k = d_in[10];
    const void* Wg_v = d_in[14]; const void* bg_v = d_in[15];

    char* ws = (char*)d_ws;
    int*    flag = (int*)ws;    ws += 16;
    float*  g9   = (float*)ws;  ws += (size_t)M_*9*4;            //   0.3 MB
    float*  part = (float*)ws;  ws += (size_t)B_*NCH_*D_*4;      //   1.0 MB
    ushort* Wt   = (ushort*)ws; ws += (size_t)K3_*K3_*2;         //  18 MB
    ushort* WoT  = (ushort*)ws; ws += (size_t)D_*D_*2;           //   2 MB
    ushort* Xc   = (ushort*)ws; ws += (size_t)M_*K3_*2;          //  50 MB (unscaled concat)
    ushort* QKV  = (ushort*)ws; ws += (size_t)M_*K3_*2;          //  50 MB
    ushort* AO   = (ushort*)ws; ws += (size_t)M_*D_*2;           //  17 MB  (total ~141 MB)

    detect_kernel<<<1, 256, 0, stream>>>((const ushort*)x, flag);
    gates_kernel<<<M_/4, 256, 0, stream>>>(x, Wg_q, bg_q, Wg_k, bg_k, Wg_v, bg_v, flag, g9);
    chunk_sum_kernel<<<dim3(D_/256, NCH_, B_), 256, 0, stream>>>(x, flag, part);
    scan_part_kernel<<<32, 64, 0, stream>>>(part);
    WPtrs wp;
    wp.w[0] = d_in[1];  wp.w[1] = d_in[2];  wp.w[2] = d_in[3];
    wp.w[3] = d_in[6];  wp.w[4] = d_in[7];  wp.w[5] = d_in[8];
    wp.w[6] = d_in[11]; wp.w[7] = d_in[12]; wp.w[8] = d_in[13];
    wp.w[9] = d_in[16];
    transpose_w_kernel<<<dim3(32, 32, 10), 256, 0, stream>>>(wp, flag, Wt, WoT);
    build_xs_kernel<<<dim3(1, NCH_, B_), 256, 0, stream>>>(x, part, flag, Xc);
    // QKV: gated GEMM, M=8192, N=3072 (3 proj x 1024), K=3072 in 3 segments
    // grid = 64 mtiles x 12 ntiles = 768 blocks = exactly 3 device-waves
    gemm_bt8_kernel<ushort, 12, true><<<768, 512, 0, stream>>>(Xc, Wt, QKV, g9, K3_, K3_, K3_);
    attn_kernel<<<B_*T_, 128, 0, stream>>>(QKV, AO);
    // out = AO @ Wo : M=8192, N=1024, K=1024  (f32 out, ungated), 256 blocks
    gemm_bt8_kernel<float, 4, false><<<256, 512, 0, stream>>>(AO, WoT, (float*)d_out, nullptr, D_, D_, D_);
}